// Round 1
// baseline (3199.482 us; speedup 1.0000x reference)
//
#include <hip/hip_runtime.h>
#include <cstdint>
#include <cstddef>

// ---------------------------------------------------------------------------
// Helpers
// ---------------------------------------------------------------------------
__device__ inline unsigned encF(float f) {
    unsigned u = __float_as_uint(f);
    return (u & 0x80000000u) ? ~u : (u | 0x80000000u);
}
__device__ inline float decF(unsigned e) {
    return (e & 0x80000000u) ? __uint_as_float(e & 0x7fffffffu)
                             : __uint_as_float(~e);
}

// ---------------------------------------------------------------------------
// Generic fp32 GEMM:  C[M x Nout] = A[M x K] @ W[Nout x K]^T + bias, act(0=id,1=relu)
// 64x64 tile, 256 threads, 4x4 per thread, K-step 16.
// ---------------------------------------------------------------------------
__global__ __launch_bounds__(256) void gemm_bias(
    const float* __restrict__ A, const float* __restrict__ W,
    const float* __restrict__ bias, float* __restrict__ C,
    int M, int K, int Nout, int act)
{
    __shared__ float As[64][17];
    __shared__ float Ws[64][17];
    const int tid = threadIdx.x;
    const int tx = tid & 15, ty = tid >> 4;
    const int m0 = blockIdx.y * 64, n0 = blockIdx.x * 64;
    const int lrow = tid >> 2;
    const int lq = (tid & 3) * 4;

    float acc[4][4] = {};

    for (int k0 = 0; k0 < K; k0 += 16) {
        // stage A tile
        {
            int m = m0 + lrow;
            float4 va = make_float4(0.f, 0.f, 0.f, 0.f);
            if (m < M) va = *(const float4*)(A + (size_t)m * K + k0 + lq);
            As[lrow][lq + 0] = va.x; As[lrow][lq + 1] = va.y;
            As[lrow][lq + 2] = va.z; As[lrow][lq + 3] = va.w;
            int n = n0 + lrow;
            float4 vw = make_float4(0.f, 0.f, 0.f, 0.f);
            if (n < Nout) vw = *(const float4*)(W + (size_t)n * K + k0 + lq);
            Ws[lrow][lq + 0] = vw.x; Ws[lrow][lq + 1] = vw.y;
            Ws[lrow][lq + 2] = vw.z; Ws[lrow][lq + 3] = vw.w;
        }
        __syncthreads();
#pragma unroll
        for (int kk = 0; kk < 16; ++kk) {
            float a[4], b[4];
#pragma unroll
            for (int i = 0; i < 4; ++i) a[i] = As[ty * 4 + i][kk];
#pragma unroll
            for (int j = 0; j < 4; ++j) b[j] = Ws[tx * 4 + j][kk];
#pragma unroll
            for (int i = 0; i < 4; ++i)
#pragma unroll
                for (int j = 0; j < 4; ++j) acc[i][j] += a[i] * b[j];
        }
        __syncthreads();
    }

#pragma unroll
    for (int i = 0; i < 4; ++i) {
        int m = m0 + ty * 4 + i;
        if (m >= M) continue;
#pragma unroll
        for (int j = 0; j < 4; ++j) {
            int n = n0 + tx * 4 + j;
            if (n >= Nout) continue;
            float v = acc[i][j] + bias[n];
            if (act == 1) v = fmaxf(v, 0.f);
            C[(size_t)m * Nout + n] = v;
        }
    }
}

// ---------------------------------------------------------------------------
// Zero-init scratch
// ---------------------------------------------------------------------------
__global__ void zero_kernel(float* __restrict__ p, size_t n)
{
    size_t i = (size_t)blockIdx.x * blockDim.x + threadIdx.x;
    size_t stride = (size_t)gridDim.x * blockDim.x;
    for (; i < n; i += stride) p[i] = 0.f;
}

// ---------------------------------------------------------------------------
// BatchNorm stats over M rows x 512 cols (row-major). Each thread owns cols
// t and t+256; block grid-strides over rows; one atomicAdd per (block,col).
// ---------------------------------------------------------------------------
__global__ __launch_bounds__(256) void bn_stats512(
    const float* __restrict__ X, float* __restrict__ sums,
    float* __restrict__ sumsq, int M)
{
    int t = threadIdx.x;
    float s0 = 0.f, q0 = 0.f, s1 = 0.f, q1 = 0.f;
    for (int r = blockIdx.x; r < M; r += gridDim.x) {
        float v0 = X[(size_t)r * 512 + t];
        float v1 = X[(size_t)r * 512 + t + 256];
        s0 += v0; q0 += v0 * v0;
        s1 += v1; q1 += v1 * v1;
    }
    atomicAdd(&sums[t], s0);
    atomicAdd(&sumsq[t], q0);
    atomicAdd(&sums[t + 256], s1);
    atomicAdd(&sumsq[t + 256], q1);
}

__global__ void bn_finalize(const float* __restrict__ sums,
                            const float* __restrict__ sumsq,
                            const float* __restrict__ g,
                            const float* __restrict__ be,
                            float* __restrict__ scale, float* __restrict__ shift,
                            int M, int C)
{
    int c = blockIdx.x * blockDim.x + threadIdx.x;
    if (c >= C) return;
    float mean = sums[c] / (float)M;
    float var = sumsq[c] / (float)M - mean * mean;
    float inv = rsqrtf(var + 1e-5f);
    float sc = g[c] * inv;
    scale[c] = sc;
    shift[c] = be[c] - mean * sc;
}

__global__ void bn_apply_sig512(float* __restrict__ X,
                                const float* __restrict__ scale,
                                const float* __restrict__ shift, size_t total)
{
    size_t i = (size_t)blockIdx.x * blockDim.x + threadIdx.x;
    size_t stride = (size_t)gridDim.x * blockDim.x;
    for (; i < total; i += stride) {
        int c = (int)(i & 511);
        float x = X[i] * scale[c] + shift[c];
        X[i] = 1.f / (1.f + expf(-x));
    }
}

// ---------------------------------------------------------------------------
// Edge kernels (TransformerConv attention). H=2 heads, F_DIM=128, HC=256.
// ---------------------------------------------------------------------------
__global__ __launch_bounds__(256) void edge_logits(
    const int* __restrict__ ei, const float* __restrict__ Q,
    const float* __restrict__ Kmat, float* __restrict__ logits,
    unsigned* __restrict__ amaxE, int E)
{
    int w = (int)(((size_t)blockIdx.x * blockDim.x + threadIdx.x) >> 6);
    int lane = threadIdx.x & 63;
    if (w >= E) return;
    int src = ei[w];
    int dst = ei[E + w];
    const float* q = Q + (size_t)dst * 256;
    const float* k = Kmat + (size_t)src * 256;
    float p0 = q[lane] * k[lane] + q[lane + 64] * k[lane + 64];
    float p1 = q[lane + 128] * k[lane + 128] + q[lane + 192] * k[lane + 192];
#pragma unroll
    for (int off = 32; off > 0; off >>= 1) {
        p0 += __shfl_down(p0, off);
        p1 += __shfl_down(p1, off);
    }
    if (lane == 0) {
        const float s = 0.088388347648318447f; // 1/sqrt(128)
        float l0 = p0 * s, l1 = p1 * s;
        logits[2 * (size_t)w] = l0;
        logits[2 * (size_t)w + 1] = l1;
        atomicMax(&amaxE[dst * 2], encF(l0));
        atomicMax(&amaxE[dst * 2 + 1], encF(l1));
    }
}

__global__ void edge_exp(const int* __restrict__ ei, float* __restrict__ logits,
                         const unsigned* __restrict__ amaxE,
                         float* __restrict__ denom, int E)
{
    int i = blockIdx.x * blockDim.x + threadIdx.x;
    if (i >= 2 * E) return;
    int e = i >> 1, h = i & 1;
    int dst = ei[E + e];
    float amax = decF(amaxE[dst * 2 + h]);
    float ex = expf(logits[i] - amax);
    logits[i] = ex;
    atomicAdd(&denom[dst * 2 + h], ex);
}

__global__ __launch_bounds__(256) void edge_message(
    const int* __restrict__ ei, const float* __restrict__ V,
    const float* __restrict__ ex, const float* __restrict__ denom,
    float* __restrict__ G, int E)
{
    int w = (int)(((size_t)blockIdx.x * blockDim.x + threadIdx.x) >> 6);
    int lane = threadIdx.x & 63;
    if (w >= E) return;
    int src = ei[w];
    int dst = ei[E + w];
    float c0 = ex[2 * (size_t)w] / fmaxf(denom[dst * 2], 1e-16f);
    float c1 = ex[2 * (size_t)w + 1] / fmaxf(denom[dst * 2 + 1], 1e-16f);
    const float* v = V + (size_t)src * 256;
    float* g = G + (size_t)dst * 256;
    atomicAdd(&g[lane], v[lane] * c0);
    atomicAdd(&g[lane + 64], v[lane + 64] * c0);
    atomicAdd(&g[lane + 128], v[lane + 128] * c1);
    atomicAdd(&g[lane + 192], v[lane + 192] * c1);
}

// ---------------------------------------------------------------------------
// h_fused = alpha*G + beta*hm (in place in G)
// ---------------------------------------------------------------------------
__global__ void fuse_kernel(float* __restrict__ G, const float* __restrict__ hm,
                            const float* __restrict__ alpha,
                            const float* __restrict__ beta, size_t total)
{
    float a = alpha[0], b = beta[0];
    size_t i = (size_t)blockIdx.x * blockDim.x + threadIdx.x;
    size_t stride = (size_t)gridDim.x * blockDim.x;
    for (; i < total; i += stride) G[i] = a * G[i] + b * hm[i];
}

// ---------------------------------------------------------------------------
// Launch
// ---------------------------------------------------------------------------
extern "C" void kernel_launch(void* const* d_in, const int* in_sizes, int n_in,
                              void* d_out, int out_size, void* d_ws, size_t ws_size,
                              hipStream_t stream)
{
    const float* x_g   = (const float*)d_in[0];
    const int*   ei    = (const int*)d_in[1];
    const float* x_m   = (const float*)d_in[2];
    const float* Wq    = (const float*)d_in[3];
    const float* bq    = (const float*)d_in[4];
    const float* Wk    = (const float*)d_in[5];
    const float* bk    = (const float*)d_in[6];
    const float* Wv    = (const float*)d_in[7];
    const float* bv    = (const float*)d_in[8];
    const float* Wskip = (const float*)d_in[9];
    const float* bskip = (const float*)d_in[10];
    const float* W1    = (const float*)d_in[11];
    const float* b1    = (const float*)d_in[12];
    const float* g1    = (const float*)d_in[13];
    const float* be1   = (const float*)d_in[14];
    const float* W2    = (const float*)d_in[15];
    const float* b2    = (const float*)d_in[16];
    const float* g2    = (const float*)d_in[17];
    const float* be2   = (const float*)d_in[18];
    const float* W3    = (const float*)d_in[19];
    const float* b3    = (const float*)d_in[20];
    const float* alpha = (const float*)d_in[21];
    const float* beta  = (const float*)d_in[22];
    const float* Wc1   = (const float*)d_in[23];
    const float* bc1   = (const float*)d_in[24];
    const float* Wc2   = (const float*)d_in[25];
    const float* bc2   = (const float*)d_in[26];
    float* out = (float*)d_out;

    const int N = in_sizes[0] / 256;
    const int E = in_sizes[1] / 2;

    float* ws = (float*)d_ws;
    const size_t nh = (size_t)N * 512;
    const size_t nq = (size_t)N * 256;

    float* h1 = ws;                 // N x 512
    float* h2 = ws + nh;            // N x 512
    float* hm = ws + 2 * nh;        // N x 256
    // after MLP branch, reuse:
    float* Q    = ws;               // N x 256 (in h1 span)
    float* Km   = ws + nq;          // N x 256 (in h1 span)
    float* V    = ws + nh;          // N x 256 (in h2 span)
    float* G    = ws + nh + nq;     // N x 256 (in h2 span)
    float* logits = ws + 2 * nh + nq;           // 2E
    unsigned* amaxE = (unsigned*)(logits + 2 * (size_t)E); // 2N
    float* denom = (float*)(amaxE + 2 * (size_t)N);        // 2N
    float* bn = denom + 2 * (size_t)N;                     // 8*512
    float* sum1 = bn, *sq1 = bn + 512, *sum2 = bn + 1024, *sq2 = bn + 1536;
    float* scale1 = bn + 2048, *shift1 = bn + 2560;
    float* scale2 = bn + 3072, *shift2 = bn + 3584;
    float* hc1 = ws;                // N x 512 (reuses Q/Km span after messages)

    dim3 blk(256);
    auto gemm = [&](const float* A, const float* W, const float* b, float* C,
                    int M, int K, int No, int act) {
        dim3 grid((No + 63) / 64, (M + 63) / 64);
        hipLaunchKernelGGL(gemm_bias, grid, blk, 0, stream, A, W, b, C, M, K, No, act);
    };

    // zero scratch that is accumulated into: amaxE(2N) + denom(2N) + bn(4096)
    hipLaunchKernelGGL(zero_kernel, dim3(256), blk, 0, stream,
                       (float*)amaxE, (size_t)(4 * (size_t)N + 4096));

    // ---- MLP branch ----
    gemm(x_m, W1, b1, h1, N, 256, 512, 0);
    hipLaunchKernelGGL(bn_stats512, dim3(1024), blk, 0, stream, h1, sum1, sq1, N);
    hipLaunchKernelGGL(bn_finalize, dim3(2), blk, 0, stream, sum1, sq1, g1, be1, scale1, shift1, N, 512);
    hipLaunchKernelGGL(bn_apply_sig512, dim3(2048), blk, 0, stream, h1, scale1, shift1, nh);
    gemm(h1, W2, b2, h2, N, 512, 512, 0);
    hipLaunchKernelGGL(bn_stats512, dim3(1024), blk, 0, stream, h2, sum2, sq2, N);
    hipLaunchKernelGGL(bn_finalize, dim3(2), blk, 0, stream, sum2, sq2, g2, be2, scale2, shift2, N, 512);
    hipLaunchKernelGGL(bn_apply_sig512, dim3(2048), blk, 0, stream, h2, scale2, shift2, nh);
    gemm(h2, W3, b3, hm, N, 512, 256, 0);

    // ---- GNN branch ----
    gemm(x_g, Wq, bq, Q, N, 256, 256, 0);
    gemm(x_g, Wk, bk, Km, N, 256, 256, 0);
    gemm(x_g, Wv, bv, V, N, 256, 256, 0);
    gemm(x_g, Wskip, bskip, G, N, 256, 256, 0);

    hipLaunchKernelGGL(edge_logits, dim3((E + 3) / 4), blk, 0, stream,
                       ei, Q, Km, logits, amaxE, E);
    hipLaunchKernelGGL(edge_exp, dim3((2 * E + 255) / 256), blk, 0, stream,
                       ei, logits, amaxE, denom, E);
    hipLaunchKernelGGL(edge_message, dim3((E + 3) / 4), blk, 0, stream,
                       ei, V, logits, denom, G, E);

    // ---- fuse + classifier ----
    hipLaunchKernelGGL(fuse_kernel, dim3(2048), blk, 0, stream, G, hm, alpha, beta, nq);
    gemm(G, Wc1, bc1, hc1, N, 256, 512, 1);
    gemm(hc1, Wc2, bc2, out, N, 512, 40, 0);
}

// Round 2
// 1179.446 us; speedup vs baseline: 2.7127x; 2.7127x over previous
//
#include <hip/hip_runtime.h>
#include <hip/hip_bf16.h>
#include <cstdint>
#include <cstddef>

typedef __attribute__((ext_vector_type(8))) short short8;
typedef __attribute__((ext_vector_type(4))) float f32x4;

__device__ inline short f2bs(float f) {
    __hip_bfloat16 h = __float2bfloat16(f);
    return *(short*)&h;
}
__device__ inline float bu2f(unsigned short u) {
    return __uint_as_float(((unsigned)u) << 16);
}

// ---------------------------------------------------------------------------
// MFMA bf16 GEMM: C[M x Nout] = A[M x K] @ W[Nout x K]^T + bias
// A: fp32 (AB=0) or bf16 (AB=1), W fp32 (converted in staging).
// 128x128 tile, 256 threads (4 waves, 2x2), BK=32, 16x16x32 MFMA.
// Epilogue: optional fp32 out Cf, optional bf16 out Cb, act(1=relu).
// ---------------------------------------------------------------------------
template <int AB>
__global__ __launch_bounds__(256) void mfma_gemm(
    const void* __restrict__ Avoid, const float* __restrict__ W,
    const float* __restrict__ bias, float* __restrict__ Cf,
    __hip_bfloat16* __restrict__ Cb, int M, int K, int Nout, int act)
{
    __shared__ short As[128][40];
    __shared__ short Bs[128][40];

    const int tid = threadIdx.x;
    const int lane = tid & 63;
    const int w = tid >> 6;
    const int wm = w >> 1, wn = w & 1;      // 2x2 waves -> 64x64 each
    const int m0 = blockIdx.y * 128, n0 = blockIdx.x * 128;

    const int trow = tid >> 1;              // 0..127
    const int tcg = (tid & 1) * 16;         // 0 or 16

    const int lr = lane & 15;
    const int lk = (lane >> 4) * 8;

    f32x4 acc[4][4] = {};

    const float* Af = (const float*)Avoid;
    const __hip_bfloat16* Ab = (const __hip_bfloat16*)Avoid;

    for (int k0 = 0; k0 < K; k0 += 32) {
        // ---- stage A tile (128 x 32) ----
        {
            short v[16];
            bool ok = (m0 + trow) < M;
            if (AB == 0) {
                const float* ap = Af + (size_t)(m0 + trow) * K + k0 + tcg;
#pragma unroll
                for (int q = 0; q < 4; ++q) {
                    float4 t4 = ok ? *(const float4*)(ap + q * 4)
                                   : make_float4(0.f, 0.f, 0.f, 0.f);
                    v[q * 4 + 0] = f2bs(t4.x); v[q * 4 + 1] = f2bs(t4.y);
                    v[q * 4 + 2] = f2bs(t4.z); v[q * 4 + 3] = f2bs(t4.w);
                }
            } else {
                const short* ap = (const short*)(Ab + (size_t)(m0 + trow) * K + k0 + tcg);
                short8 s0 = {}, s1 = {};
                if (ok) { s0 = *(const short8*)(ap); s1 = *(const short8*)(ap + 8); }
#pragma unroll
                for (int j = 0; j < 8; ++j) { v[j] = s0[j]; v[8 + j] = s1[j]; }
            }
            short8 w0, w1;
#pragma unroll
            for (int j = 0; j < 8; ++j) { w0[j] = v[j]; w1[j] = v[j + 8]; }
            *(short8*)&As[trow][tcg] = w0;
            *(short8*)&As[trow][tcg + 8] = w1;
        }
        // ---- stage B tile (128 x 32) from W fp32 ----
        {
            short v[16];
            bool ok = (n0 + trow) < Nout;
            const float* wp = W + (size_t)(n0 + trow) * K + k0 + tcg;
#pragma unroll
            for (int q = 0; q < 4; ++q) {
                float4 t4 = ok ? *(const float4*)(wp + q * 4)
                               : make_float4(0.f, 0.f, 0.f, 0.f);
                v[q * 4 + 0] = f2bs(t4.x); v[q * 4 + 1] = f2bs(t4.y);
                v[q * 4 + 2] = f2bs(t4.z); v[q * 4 + 3] = f2bs(t4.w);
            }
            short8 w0, w1;
#pragma unroll
            for (int j = 0; j < 8; ++j) { w0[j] = v[j]; w1[j] = v[j + 8]; }
            *(short8*)&Bs[trow][tcg] = w0;
            *(short8*)&Bs[trow][tcg + 8] = w1;
        }
        __syncthreads();

        short8 afr[4], bfr[4];
#pragma unroll
        for (int mi = 0; mi < 4; ++mi)
            afr[mi] = *(const short8*)&As[wm * 64 + mi * 16 + lr][lk];
#pragma unroll
        for (int nj = 0; nj < 4; ++nj)
            bfr[nj] = *(const short8*)&Bs[wn * 64 + nj * 16 + lr][lk];
#pragma unroll
        for (int mi = 0; mi < 4; ++mi)
#pragma unroll
            for (int nj = 0; nj < 4; ++nj)
                acc[mi][nj] = __builtin_amdgcn_mfma_f32_16x16x32_bf16(
                    afr[mi], bfr[nj], acc[mi][nj], 0, 0, 0);
        __syncthreads();
    }

    // ---- epilogue: C/D layout col=lane&15, row=(lane>>4)*4+r ----
#pragma unroll
    for (int mi = 0; mi < 4; ++mi) {
#pragma unroll
        for (int nj = 0; nj < 4; ++nj) {
            int gn = n0 + wn * 64 + nj * 16 + lr;
            if (gn >= Nout) continue;
            float b = bias[gn];
#pragma unroll
            for (int r = 0; r < 4; ++r) {
                int gm = m0 + wm * 64 + mi * 16 + (lane >> 4) * 4 + r;
                if (gm >= M) continue;
                float v = acc[mi][nj][r] + b;
                if (act == 1) v = fmaxf(v, 0.f);
                if (Cf) Cf[(size_t)gm * Nout + gn] = v;
                if (Cb) Cb[(size_t)gm * Nout + gn] = __float2bfloat16(v);
            }
        }
    }
}

// ---------------------------------------------------------------------------
// misc small kernels
// ---------------------------------------------------------------------------
__global__ void zero_words(unsigned* __restrict__ p, size_t n)
{
    size_t i = (size_t)blockIdx.x * blockDim.x + threadIdx.x;
    size_t stride = (size_t)gridDim.x * blockDim.x;
    for (; i < n; i += stride) p[i] = 0u;
}

__global__ __launch_bounds__(256) void bn_stats512(
    const float* __restrict__ X, float* __restrict__ sums,
    float* __restrict__ sumsq, int M)
{
    int t = threadIdx.x;
    float s0 = 0.f, q0 = 0.f, s1 = 0.f, q1 = 0.f;
    for (int r = blockIdx.x; r < M; r += gridDim.x) {
        float v0 = X[(size_t)r * 512 + t];
        float v1 = X[(size_t)r * 512 + t + 256];
        s0 += v0; q0 += v0 * v0;
        s1 += v1; q1 += v1 * v1;
    }
    atomicAdd(&sums[t], s0);
    atomicAdd(&sumsq[t], q0);
    atomicAdd(&sums[t + 256], s1);
    atomicAdd(&sumsq[t + 256], q1);
}

__global__ void bn_finalize(const float* __restrict__ sums,
                            const float* __restrict__ sumsq,
                            const float* __restrict__ g,
                            const float* __restrict__ be,
                            float* __restrict__ scale, float* __restrict__ shift,
                            int M, int C)
{
    int c = blockIdx.x * blockDim.x + threadIdx.x;
    if (c >= C) return;
    float mean = sums[c] / (float)M;
    float var = sumsq[c] / (float)M - mean * mean;
    float inv = rsqrtf(var + 1e-5f);
    float sc = g[c] * inv;
    scale[c] = sc;
    shift[c] = be[c] - mean * sc;
}

__global__ void bn_apply_sig512_b(const float* __restrict__ X,
                                  __hip_bfloat16* __restrict__ Y,
                                  const float* __restrict__ scale,
                                  const float* __restrict__ shift, size_t total)
{
    size_t i = (size_t)blockIdx.x * blockDim.x + threadIdx.x;
    size_t stride = (size_t)gridDim.x * blockDim.x;
    for (; i < total; i += stride) {
        int c = (int)(i & 511);
        float x = X[i] * scale[c] + shift[c];
        Y[i] = __float2bfloat16(1.f / (1.f + __expf(-x)));
    }
}

// ---------------------------------------------------------------------------
// CSR build
// ---------------------------------------------------------------------------
__global__ void count_edges(const int* __restrict__ ei, int* __restrict__ counts, int E)
{
    int i = blockIdx.x * 256 + threadIdx.x;
    if (i < E) atomicAdd(&counts[ei[E + i]], 1);
}

__global__ __launch_bounds__(256) void scan_local(
    const int* __restrict__ cnt, int* __restrict__ excl,
    int* __restrict__ bsums, int n)
{
    __shared__ int s[256];
    int t = threadIdx.x;
    int i = blockIdx.x * 256 + t;
    int v = (i < n) ? cnt[i] : 0;
    s[t] = v;
    __syncthreads();
    for (int off = 1; off < 256; off <<= 1) {
        int u = (t >= off) ? s[t - off] : 0;
        __syncthreads();
        s[t] += u;
        __syncthreads();
    }
    if (i < n) excl[i] = s[t] - v;
    if (t == 255) bsums[blockIdx.x] = s[255];
}

__global__ __launch_bounds__(256) void scan_top(int* __restrict__ bsums, int nb)
{
    __shared__ int s[256];
    int t = threadIdx.x;
    int v = (t < nb) ? bsums[t] : 0;
    s[t] = v;
    __syncthreads();
    for (int off = 1; off < 256; off <<= 1) {
        int u = (t >= off) ? s[t - off] : 0;
        __syncthreads();
        s[t] += u;
        __syncthreads();
    }
    if (t < nb) bsums[t] = s[t] - v;
}

__global__ void scan_add(int* __restrict__ excl, const int* __restrict__ bsums,
                         int* __restrict__ cursor, int n)
{
    int i = blockIdx.x * 256 + threadIdx.x;
    if (i < n) {
        int v = excl[i] + bsums[blockIdx.x];
        excl[i] = v;
        cursor[i] = v;
    }
}

__global__ void fill_edges(const int* __restrict__ ei, int* __restrict__ cursor,
                           int* __restrict__ esrc, int E)
{
    int i = blockIdx.x * 256 + threadIdx.x;
    if (i < E) {
        int dst = ei[E + i];
        int pos = atomicAdd(&cursor[dst], 1);
        esrc[pos] = ei[i];
    }
}

// ---------------------------------------------------------------------------
// Fused TransformerConv attention: one wave per dst node, online softmax.
// lanes 0-31: head 0 (dims 0..127), lanes 32-63: head 1 (dims 128..255).
// Q fp32, K/V bf16. Writes G = aggregated message (fp32).
// ---------------------------------------------------------------------------
__global__ __launch_bounds__(256) void edge_attn(
    const int* __restrict__ esrc, const int* __restrict__ offs,
    const int* __restrict__ cnts, const float* __restrict__ Q,
    const __hip_bfloat16* __restrict__ Kb, const __hip_bfloat16* __restrict__ Vb,
    float* __restrict__ G, int N)
{
    int node = blockIdx.x * 4 + (threadIdx.x >> 6);
    int lane = threadIdx.x & 63;
    if (node >= N) return;
    int start = offs[node];
    int cnt = cnts[node];

    float4 qv = *(const float4*)(Q + (size_t)node * 256 + lane * 4);
    const float s = 0.088388347648318447f; // 1/sqrt(128)

    float m = -INFINITY, d = 0.f;
    float a0 = 0.f, a1 = 0.f, a2 = 0.f, a3 = 0.f;

    for (int i = 0; i < cnt; ++i) {
        int src = esrc[start + i];
        const ushort4 ku = *(const ushort4*)(Kb + (size_t)src * 256 + lane * 4);
        float p = qv.x * bu2f(ku.x) + qv.y * bu2f(ku.y)
                + qv.z * bu2f(ku.z) + qv.w * bu2f(ku.w);
        p += __shfl_xor(p, 1);
        p += __shfl_xor(p, 2);
        p += __shfl_xor(p, 4);
        p += __shfl_xor(p, 8);
        p += __shfl_xor(p, 16);
        float l = p * s;
        float mn = fmaxf(m, l);
        float sc = __expf(m - mn);
        float pe = __expf(l - mn);
        const ushort4 vu = *(const ushort4*)(Vb + (size_t)src * 256 + lane * 4);
        d = d * sc + pe;
        a0 = a0 * sc + pe * bu2f(vu.x);
        a1 = a1 * sc + pe * bu2f(vu.y);
        a2 = a2 * sc + pe * bu2f(vu.z);
        a3 = a3 * sc + pe * bu2f(vu.w);
        m = mn;
    }
    float invd = (cnt > 0) ? 1.f / fmaxf(d, 1e-16f) : 0.f;
    float4 o = make_float4(a0 * invd, a1 * invd, a2 * invd, a3 * invd);
    *(float4*)(G + (size_t)node * 256 + lane * 4) = o;
}

// ---------------------------------------------------------------------------
// hf = alpha*(G + skip) + beta*hm  -> bf16
// ---------------------------------------------------------------------------
__global__ void fuse_b(const float* __restrict__ G,
                       const __hip_bfloat16* __restrict__ S,
                       const __hip_bfloat16* __restrict__ hm,
                       const float* __restrict__ alpha,
                       const float* __restrict__ beta,
                       __hip_bfloat16* __restrict__ out, size_t total)
{
    float a = alpha[0], b = beta[0];
    size_t i = (size_t)blockIdx.x * blockDim.x + threadIdx.x;
    size_t stride = (size_t)gridDim.x * blockDim.x;
    for (; i < total; i += stride)
        out[i] = __float2bfloat16(a * (G[i] + __bfloat162float(S[i]))
                                  + b * __bfloat162float(hm[i]));
}

// ---------------------------------------------------------------------------
// Launch
// ---------------------------------------------------------------------------
extern "C" void kernel_launch(void* const* d_in, const int* in_sizes, int n_in,
                              void* d_out, int out_size, void* d_ws, size_t ws_size,
                              hipStream_t stream)
{
    const float* x_g   = (const float*)d_in[0];
    const int*   ei    = (const int*)d_in[1];
    const float* x_m   = (const float*)d_in[2];
    const float* Wq    = (const float*)d_in[3];
    const float* bq    = (const float*)d_in[4];
    const float* Wk    = (const float*)d_in[5];
    const float* bk    = (const float*)d_in[6];
    const float* Wv    = (const float*)d_in[7];
    const float* bv    = (const float*)d_in[8];
    const float* Wskip = (const float*)d_in[9];
    const float* bskip = (const float*)d_in[10];
    const float* W1    = (const float*)d_in[11];
    const float* b1    = (const float*)d_in[12];
    const float* g1    = (const float*)d_in[13];
    const float* be1   = (const float*)d_in[14];
    const float* W2    = (const float*)d_in[15];
    const float* b2    = (const float*)d_in[16];
    const float* g2    = (const float*)d_in[17];
    const float* be2   = (const float*)d_in[18];
    const float* W3    = (const float*)d_in[19];
    const float* b3    = (const float*)d_in[20];
    const float* alpha = (const float*)d_in[21];
    const float* beta  = (const float*)d_in[22];
    const float* Wc1   = (const float*)d_in[23];
    const float* bc1   = (const float*)d_in[24];
    const float* Wc2   = (const float*)d_in[25];
    const float* bc2   = (const float*)d_in[26];
    float* out = (float*)d_out;

    const int N = in_sizes[0] / 256;
    const int E = in_sizes[1] / 2;

    const size_t nq = (size_t)N * 256;
    const size_t nh = (size_t)N * 512;

    float* ws = (float*)d_ws;
    float* Abuf = ws;                        // nh floats (102.4MB)
    float* Bbuf = ws + nh;                   // nq floats (h1b/h2b/S_b bf16 area)
    float* Cbuf = ws + nh + nq;              // nq/2 floats (hm_b bf16)
    float* Ebuf = ws + nh + nq + nq / 2;     // nq floats (G fp32)
    float* Fbuf = ws + nh + 2 * nq + nq / 2; // stats + CSR

    // F layout: [sums1 512][sq1 512][sums2 512][sq2 512][counts N]
    //           [scale1 512][shift1 512][scale2 512][shift2 512]
    //           [bsums 256][offsets N][cursor N][esrc E]
    float* sum1 = Fbuf, *sq1 = Fbuf + 512, *sum2 = Fbuf + 1024, *sq2 = Fbuf + 1536;
    int* counts = (int*)(Fbuf + 2048);
    float* base2 = Fbuf + 2048 + N;
    float* scale1 = base2, *shift1 = base2 + 512;
    float* scale2 = base2 + 1024, *shift2 = base2 + 1536;
    int* bsums = (int*)(base2 + 2048);
    int* offs = bsums + 256;
    int* cursor = offs + N;
    int* esrc = cursor + N;

    // region-A sub-buffers (GNN phase)
    float* Qf = Abuf;                                        // nq fp32
    __hip_bfloat16* Kb = (__hip_bfloat16*)(Abuf + nq);       // nq bf16
    __hip_bfloat16* Vb = (__hip_bfloat16*)(Abuf + nq + nq / 2);
    __hip_bfloat16* hfb = (__hip_bfloat16*)Abuf;             // after edge phase
    __hip_bfloat16* hc1b = (__hip_bfloat16*)(Abuf + nq / 2);
    __hip_bfloat16* h12b = (__hip_bfloat16*)Bbuf;            // h1b then h2b
    __hip_bfloat16* Sb = (__hip_bfloat16*)Bbuf;              // after h2b dead
    __hip_bfloat16* hmb = (__hip_bfloat16*)Cbuf;
    float* G = Ebuf;

    dim3 blk(256);
    auto gemm = [&](int ab, const void* A, const float* W, const float* b,
                    float* Cf, __hip_bfloat16* Cb, int M, int K, int No, int act) {
        dim3 grid((No + 127) / 128, (M + 127) / 128);
        if (ab == 0)
            hipLaunchKernelGGL(mfma_gemm<0>, grid, blk, 0, stream, A, W, b, Cf, Cb, M, K, No, act);
        else
            hipLaunchKernelGGL(mfma_gemm<1>, grid, blk, 0, stream, A, W, b, Cf, Cb, M, K, No, act);
    };

    // ---- zero accumulators: sums/sq (2048 f32) + counts (N i32), contiguous ----
    hipLaunchKernelGGL(zero_words, dim3(128), blk, 0, stream,
                       (unsigned*)Fbuf, (size_t)(2048 + N));

    // ---- CSR build ----
    const int nb = (N + 255) / 256;
    hipLaunchKernelGGL(count_edges, dim3((E + 255) / 256), blk, 0, stream, ei, counts, E);
    hipLaunchKernelGGL(scan_local, dim3(nb), blk, 0, stream, counts, offs, bsums, N);
    hipLaunchKernelGGL(scan_top, dim3(1), blk, 0, stream, bsums, nb);
    hipLaunchKernelGGL(scan_add, dim3(nb), blk, 0, stream, offs, bsums, cursor, N);
    hipLaunchKernelGGL(fill_edges, dim3((E + 255) / 256), blk, 0, stream, ei, cursor, esrc, E);

    // ---- MLP branch ----
    gemm(0, x_m, W1, b1, Abuf, nullptr, N, 256, 512, 0);
    hipLaunchKernelGGL(bn_stats512, dim3(1024), blk, 0, stream, Abuf, sum1, sq1, N);
    hipLaunchKernelGGL(bn_finalize, dim3(2), blk, 0, stream, sum1, sq1, g1, be1, scale1, shift1, N, 512);
    hipLaunchKernelGGL(bn_apply_sig512_b, dim3(2048), blk, 0, stream, Abuf, h12b, scale1, shift1, nh);
    gemm(1, h12b, W2, b2, Abuf, nullptr, N, 512, 512, 0);
    hipLaunchKernelGGL(bn_stats512, dim3(1024), blk, 0, stream, Abuf, sum2, sq2, N);
    hipLaunchKernelGGL(bn_finalize, dim3(2), blk, 0, stream, sum2, sq2, g2, be2, scale2, shift2, N, 512);
    hipLaunchKernelGGL(bn_apply_sig512_b, dim3(2048), blk, 0, stream, Abuf, h12b, scale2, shift2, nh);
    gemm(1, h12b, W3, b3, nullptr, hmb, N, 512, 256, 0);

    // ---- GNN branch: Q fp32, K/V/skip bf16 ----
    gemm(0, x_g, Wq, bq, Qf, nullptr, N, 256, 256, 0);
    gemm(0, x_g, Wk, bk, nullptr, Kb, N, 256, 256, 0);
    gemm(0, x_g, Wv, bv, nullptr, Vb, N, 256, 256, 0);
    gemm(0, x_g, Wskip, bskip, nullptr, Sb, N, 256, 256, 0);

    hipLaunchKernelGGL(edge_attn, dim3((N + 3) / 4), blk, 0, stream,
                       esrc, offs, counts, Qf, Kb, Vb, G, N);

    // ---- fuse + classifier ----
    hipLaunchKernelGGL(fuse_b, dim3(2048), blk, 0, stream, G, Sb, hmb, alpha, beta, hfb, nq);
    gemm(1, hfb, Wc1, bc1, nullptr, hc1b, N, 256, 512, 1);
    gemm(1, hc1b, Wc2, bc2, out, nullptr, N, 512, 40, 0);
}

// Round 4
// 940.892 us; speedup vs baseline: 3.4005x; 1.2535x over previous
//
#include <hip/hip_runtime.h>
#include <hip/hip_bf16.h>
#include <cstdint>
#include <cstddef>

typedef __attribute__((ext_vector_type(8))) short short8;
typedef __attribute__((ext_vector_type(4))) float f32x4;

__device__ inline ushort f2bs(float f) {
    __hip_bfloat16 h = __float2bfloat16(f);
    return *(ushort*)&h;
}
__device__ inline float bu2f(ushort u) {
    return __uint_as_float(((unsigned)u) << 16);
}

// ---------------------------------------------------------------------------
// Full-K-in-LDS MFMA GEMM.  C[M x NT*128] = A[M x KT] @ Wb[NT*128 x KT]^T + bias
// A fp32 (AB=0) or bf16 (AB=1); Wb bf16 (pre-converted, L2-hot).
// Block: BM rows, 256 threads (4 waves as 2x2).  A panel staged ONCE in LDS,
// then loop over NT col-tiles x (KT/32) K-steps.  C written bf16.
// ---------------------------------------------------------------------------
template <int AB, int BM, int KT>
__global__ __launch_bounds__(256) void gemm_fullk(
    const void* __restrict__ Avoid, const short* __restrict__ Wb,
    const float* __restrict__ bias, ushort* __restrict__ C,
    int M, int NT, int act)
{
    __shared__ short As[BM][KT + 8];
    __shared__ short Bs[128][40];

    const int tid = threadIdx.x;
    const int lane = tid & 63;
    const int w = tid >> 6;
    const int wm = w >> 1, wn = w & 1;
    constexpr int MI = BM / 32;            // M-frags per wave
    const int m0 = blockIdx.x * BM;
    const int lr = lane & 15;
    const int lk = (lane >> 4) * 8;
    const int Ntot = NT * 128;

    // ---- stage the full A panel (BM x KT) ----
    {
        constexpr int TPR = KT / 128;       // threads per row
        const int arow = tid / TPR;
        const int ac0 = (tid % TPR) * 128;
        const bool ok = (m0 + arow) < M;
        if (AB == 0) {
            const float* ap = (const float*)Avoid + (size_t)(m0 + arow) * KT + ac0;
#pragma unroll
            for (int j = 0; j < 16; ++j) {
                float4 x = ok ? *(const float4*)(ap + j * 8)
                              : make_float4(0.f, 0.f, 0.f, 0.f);
                float4 y = ok ? *(const float4*)(ap + j * 8 + 4)
                              : make_float4(0.f, 0.f, 0.f, 0.f);
                short8 v;
                v[0] = f2bs(x.x); v[1] = f2bs(x.y); v[2] = f2bs(x.z); v[3] = f2bs(x.w);
                v[4] = f2bs(y.x); v[5] = f2bs(y.y); v[6] = f2bs(y.z); v[7] = f2bs(y.w);
                *(short8*)&As[arow][ac0 + j * 8] = v;
            }
        } else {
            const short* ap = (const short*)Avoid + (size_t)(m0 + arow) * KT + ac0;
#pragma unroll
            for (int j = 0; j < 16; ++j) {
                short8 v = {};
                if (ok) v = *(const short8*)(ap + j * 8);
                *(short8*)&As[arow][ac0 + j * 8] = v;
            }
        }
    }

    const int trow = tid >> 1;
    const int tcg = (tid & 1) * 16;

    f32x4 acc[MI][4] = {};

    for (int t = 0; t < NT; ++t) {
        for (int k0 = 0; k0 < KT; k0 += 32) {
            // stage B tile (128 x 32) bf16 from L2-hot weights
            const short* wp = Wb + (size_t)(t * 128 + trow) * KT + k0 + tcg;
            *(short8*)&Bs[trow][tcg] = *(const short8*)wp;
            *(short8*)&Bs[trow][tcg + 8] = *(const short8*)(wp + 8);
            __syncthreads();

            short8 afr[MI], bfr[4];
#pragma unroll
            for (int mi = 0; mi < MI; ++mi)
                afr[mi] = *(const short8*)&As[wm * (BM / 2) + mi * 16 + lr][k0 + lk];
#pragma unroll
            for (int nj = 0; nj < 4; ++nj)
                bfr[nj] = *(const short8*)&Bs[wn * 64 + nj * 16 + lr][lk];
#pragma unroll
            for (int mi = 0; mi < MI; ++mi)
#pragma unroll
                for (int nj = 0; nj < 4; ++nj)
                    acc[mi][nj] = __builtin_amdgcn_mfma_f32_16x16x32_bf16(
                        afr[mi], bfr[nj], acc[mi][nj], 0, 0, 0);
            __syncthreads();
        }
        // epilogue for col-tile t
#pragma unroll
        for (int mi = 0; mi < MI; ++mi) {
#pragma unroll
            for (int nj = 0; nj < 4; ++nj) {
                int gn = t * 128 + wn * 64 + nj * 16 + lr;
                float b = bias[gn];
#pragma unroll
                for (int r = 0; r < 4; ++r) {
                    int gm = m0 + wm * (BM / 2) + mi * 16 + (lane >> 4) * 4 + r;
                    if (gm < M) {
                        float v = acc[mi][nj][r] + b;
                        if (act == 1) v = fmaxf(v, 0.f);
                        C[(size_t)gm * Ntot + gn] = f2bs(v);
                    }
                }
                acc[mi][nj] = (f32x4){0.f, 0.f, 0.f, 0.f};
            }
        }
    }
}

// ---------------------------------------------------------------------------
// Legacy 128x128 GEMM (kept for the tiny Wc2: N=40, fp32 out, W fp32)
// ---------------------------------------------------------------------------
__global__ __launch_bounds__(256) void mfma_gemm_small(
    const short* __restrict__ A, const float* __restrict__ W,
    const float* __restrict__ bias, float* __restrict__ Cf,
    int M, int K, int Nout)
{
    __shared__ short As[128][40];
    __shared__ short Bs[128][40];
    const int tid = threadIdx.x;
    const int lane = tid & 63;
    const int w = tid >> 6;
    const int wm = w >> 1, wn = w & 1;
    const int m0 = blockIdx.y * 128, n0 = blockIdx.x * 128;
    const int trow = tid >> 1;
    const int tcg = (tid & 1) * 16;
    const int lr = lane & 15;
    const int lk = (lane >> 4) * 8;

    f32x4 acc[4][4] = {};

    for (int k0 = 0; k0 < K; k0 += 32) {
        {
            bool ok = (m0 + trow) < M;
            const short* ap = A + (size_t)(m0 + trow) * K + k0 + tcg;
            short8 s0 = {}, s1 = {};
            if (ok) { s0 = *(const short8*)(ap); s1 = *(const short8*)(ap + 8); }
            *(short8*)&As[trow][tcg] = s0;
            *(short8*)&As[trow][tcg + 8] = s1;
        }
        {
            short v[16];
            bool ok = (n0 + trow) < Nout;
            const float* wp = W + (size_t)(n0 + trow) * K + k0 + tcg;
#pragma unroll
            for (int q = 0; q < 4; ++q) {
                float4 t4 = ok ? *(const float4*)(wp + q * 4)
                               : make_float4(0.f, 0.f, 0.f, 0.f);
                v[q * 4 + 0] = f2bs(t4.x); v[q * 4 + 1] = f2bs(t4.y);
                v[q * 4 + 2] = f2bs(t4.z); v[q * 4 + 3] = f2bs(t4.w);
            }
            short8 w0, w1;
#pragma unroll
            for (int j = 0; j < 8; ++j) { w0[j] = v[j]; w1[j] = v[j + 8]; }
            *(short8*)&Bs[trow][tcg] = w0;
            *(short8*)&Bs[trow][tcg + 8] = w1;
        }
        __syncthreads();
        short8 afr[4], bfr[4];
#pragma unroll
        for (int mi = 0; mi < 4; ++mi)
            afr[mi] = *(const short8*)&As[wm * 64 + mi * 16 + lr][lk];
#pragma unroll
        for (int nj = 0; nj < 4; ++nj)
            bfr[nj] = *(const short8*)&Bs[wn * 64 + nj * 16 + lr][lk];
#pragma unroll
        for (int mi = 0; mi < 4; ++mi)
#pragma unroll
            for (int nj = 0; nj < 4; ++nj)
                acc[mi][nj] = __builtin_amdgcn_mfma_f32_16x16x32_bf16(
                    afr[mi], bfr[nj], acc[mi][nj], 0, 0, 0);
        __syncthreads();
    }
#pragma unroll
    for (int mi = 0; mi < 4; ++mi)
#pragma unroll
        for (int nj = 0; nj < 4; ++nj) {
            int gn = n0 + wn * 64 + nj * 16 + lr;
            if (gn >= Nout) continue;
            float b = bias[gn];
#pragma unroll
            for (int r = 0; r < 4; ++r) {
                int gm = m0 + wm * 64 + mi * 16 + (lane >> 4) * 4 + r;
                if (gm < M) Cf[(size_t)gm * Nout + gn] = acc[mi][nj][r] + b;
            }
        }
}

// ---------------------------------------------------------------------------
// small utility kernels
// ---------------------------------------------------------------------------
__global__ void zero_words(unsigned* __restrict__ p, size_t n)
{
    size_t i = (size_t)blockIdx.x * blockDim.x + threadIdx.x;
    size_t stride = (size_t)gridDim.x * blockDim.x;
    for (; i < n; i += stride) p[i] = 0u;
}

__global__ void cvt_f32_bf16(const float* __restrict__ s, ushort* __restrict__ d,
                             size_t n4)
{
    size_t i = (size_t)blockIdx.x * blockDim.x + threadIdx.x;
    size_t stride = (size_t)gridDim.x * blockDim.x;
    for (; i < n4; i += stride) {
        float4 v = ((const float4*)s)[i];
        ushort4 o;
        o.x = f2bs(v.x); o.y = f2bs(v.y); o.z = f2bs(v.z); o.w = f2bs(v.w);
        ((ushort4*)d)[i] = o;
    }
}

__global__ void copy_f32(const float* __restrict__ s, float* __restrict__ d, int n)
{
    int i = blockIdx.x * blockDim.x + threadIdx.x;
    if (i < n) d[i] = s[i];
}

__global__ __launch_bounds__(256) void bn_stats512_b(
    const ushort* __restrict__ X, float* __restrict__ sums,
    float* __restrict__ sumsq, int M)
{
    int t = threadIdx.x;  // cols 2t, 2t+1
    float s0 = 0.f, q0 = 0.f, s1 = 0.f, q1 = 0.f;
    for (int r = blockIdx.x; r < M; r += gridDim.x) {
        ushort2 v = *(const ushort2*)(X + (size_t)r * 512 + 2 * t);
        float a = bu2f(v.x), b = bu2f(v.y);
        s0 += a; q0 += a * a;
        s1 += b; q1 += b * b;
    }
    atomicAdd(&sums[2 * t], s0);
    atomicAdd(&sumsq[2 * t], q0);
    atomicAdd(&sums[2 * t + 1], s1);
    atomicAdd(&sumsq[2 * t + 1], q1);
}

__global__ void bn_finalize(const float* __restrict__ sums,
                            const float* __restrict__ sumsq,
                            const float* __restrict__ g,
                            const float* __restrict__ be,
                            float* __restrict__ scale, float* __restrict__ shift,
                            int M, int C)
{
    int c = blockIdx.x * blockDim.x + threadIdx.x;
    if (c >= C) return;
    float mean = sums[c] / (float)M;
    float var = sumsq[c] / (float)M - mean * mean;
    float inv = rsqrtf(var + 1e-5f);
    float sc = g[c] * inv;
    scale[c] = sc;
    shift[c] = be[c] - mean * sc;
}

// in-place BN + sigmoid on bf16, vectorized x4 (512 cols)
__global__ void bn_apply_sig4(ushort* __restrict__ X,
                              const float* __restrict__ scale,
                              const float* __restrict__ shift, size_t n4)
{
    size_t i = (size_t)blockIdx.x * blockDim.x + threadIdx.x;
    size_t stride = (size_t)gridDim.x * blockDim.x;
    for (; i < n4; i += stride) {
        ushort4 v = ((ushort4*)X)[i];
        int c0 = (int)((i * 4) & 511);
        float x0 = bu2f(v.x) * scale[c0] + shift[c0];
        float x1 = bu2f(v.y) * scale[c0 + 1] + shift[c0 + 1];
        float x2 = bu2f(v.z) * scale[c0 + 2] + shift[c0 + 2];
        float x3 = bu2f(v.w) * scale[c0 + 3] + shift[c0 + 3];
        v.x = f2bs(1.f / (1.f + __expf(-x0)));
        v.y = f2bs(1.f / (1.f + __expf(-x1)));
        v.z = f2bs(1.f / (1.f + __expf(-x2)));
        v.w = f2bs(1.f / (1.f + __expf(-x3)));
        ((ushort4*)X)[i] = v;
    }
}

// ---------------------------------------------------------------------------
// CSR build
// ---------------------------------------------------------------------------
__global__ void count_edges(const int* __restrict__ ei, int* __restrict__ counts, int E)
{
    int i = blockIdx.x * 256 + threadIdx.x;
    if (i < E) atomicAdd(&counts[ei[E + i]], 1);
}

__global__ __launch_bounds__(256) void scan_local(
    const int* __restrict__ cnt, int* __restrict__ excl,
    int* __restrict__ bsums, int n)
{
    __shared__ int s[256];
    int t = threadIdx.x;
    int i = blockIdx.x * 256 + t;
    int v = (i < n) ? cnt[i] : 0;
    s[t] = v;
    __syncthreads();
    for (int off = 1; off < 256; off <<= 1) {
        int u = (t >= off) ? s[t - off] : 0;
        __syncthreads();
        s[t] += u;
        __syncthreads();
    }
    if (i < n) excl[i] = s[t] - v;
    if (t == 255) bsums[blockIdx.x] = s[255];
}

__global__ __launch_bounds__(256) void scan_top(int* __restrict__ bsums, int nb)
{
    __shared__ int s[256];
    int t = threadIdx.x;
    int v = (t < nb) ? bsums[t] : 0;
    s[t] = v;
    __syncthreads();
    for (int off = 1; off < 256; off <<= 1) {
        int u = (t >= off) ? s[t - off] : 0;
        __syncthreads();
        s[t] += u;
        __syncthreads();
    }
    if (t < nb) bsums[t] = s[t] - v;
}

__global__ void scan_add(int* __restrict__ excl, const int* __restrict__ bsums,
                         int* __restrict__ cursor, int n)
{
    int i = blockIdx.x * 256 + threadIdx.x;
    if (i < n) {
        int v = excl[i] + bsums[blockIdx.x];
        excl[i] = v;
        cursor[i] = v;
    }
}

__global__ void fill_edges(const int* __restrict__ ei, int* __restrict__ cursor,
                           int* __restrict__ esrc, int E)
{
    int i = blockIdx.x * 256 + threadIdx.x;
    if (i < E) {
        int dst = ei[E + i];
        int pos = atomicAdd(&cursor[dst], 1);
        esrc[pos] = ei[i];
    }
}

// ---------------------------------------------------------------------------
// Fused attention + skip + hm fusion.  One wave per dst node; QKVS layout per
// node: [Q 256 | K 256 | V 256 | S 256] bf16 (K||V contiguous 1KB per edge).
// lanes 0-31: head 0, lanes 32-63: head 1.  hf = alpha*(msg + S) + beta*hm.
// ---------------------------------------------------------------------------
__global__ __launch_bounds__(256) void edge_attn(
    const int* __restrict__ esrc, const int* __restrict__ offs,
    const int* __restrict__ cnts, const ushort* __restrict__ QKVS,
    const ushort* __restrict__ hmb, const float* __restrict__ alpha,
    const float* __restrict__ beta, ushort* __restrict__ hf, int N)
{
    int node = blockIdx.x * 4 + (threadIdx.x >> 6);
    int lane = threadIdx.x & 63;
    if (node >= N) return;
    int start = offs[node];
    int cnt = cnts[node];

    ushort4 qu = *(const ushort4*)(QKVS + (size_t)node * 1024 + lane * 4);
    float qx = bu2f(qu.x), qy = bu2f(qu.y), qz = bu2f(qu.z), qw = bu2f(qu.w);
    const float s = 0.088388347648318447f; // 1/sqrt(128)

    float m = -INFINITY, d = 0.f;
    float a0 = 0.f, a1 = 0.f, a2 = 0.f, a3 = 0.f;

    ushort4 ku_n = {}, vu_n = {};
    if (cnt > 0) {
        int src0 = esrc[start];
        ku_n = *(const ushort4*)(QKVS + (size_t)src0 * 1024 + 256 + lane * 4);
        vu_n = *(const ushort4*)(QKVS + (size_t)src0 * 1024 + 512 + lane * 4);
    }
    for (int i = 0; i < cnt; ++i) {
        ushort4 ku = ku_n, vu = vu_n;
        if (i + 1 < cnt) {
            int srcn = esrc[start + i + 1];
            ku_n = *(const ushort4*)(QKVS + (size_t)srcn * 1024 + 256 + lane * 4);
            vu_n = *(const ushort4*)(QKVS + (size_t)srcn * 1024 + 512 + lane * 4);
        }
        float p = qx * bu2f(ku.x) + qy * bu2f(ku.y)
                + qz * bu2f(ku.z) + qw * bu2f(ku.w);
        p += __shfl_xor(p, 1);
        p += __shfl_xor(p, 2);
        p += __shfl_xor(p, 4);
        p += __shfl_xor(p, 8);
        p += __shfl_xor(p, 16);
        float l = p * s;
        float mn = fmaxf(m, l);
        float sc = __expf(m - mn);
        float pe = __expf(l - mn);
        d = d * sc + pe;
        a0 = a0 * sc + pe * bu2f(vu.x);
        a1 = a1 * sc + pe * bu2f(vu.y);
        a2 = a2 * sc + pe * bu2f(vu.z);
        a3 = a3 * sc + pe * bu2f(vu.w);
        m = mn;
    }
    float invd = (cnt > 0) ? 1.f / fmaxf(d, 1e-16f) : 0.f;
    float o0 = a0 * invd, o1 = a1 * invd, o2 = a2 * invd, o3 = a3 * invd;

    ushort4 su = *(const ushort4*)(QKVS + (size_t)node * 1024 + 768 + lane * 4);
    ushort4 hm = *(const ushort4*)(hmb + (size_t)node * 256 + lane * 4);
    float al = alpha[0], be = beta[0];
    ushort4 o;
    o.x = f2bs(al * (o0 + bu2f(su.x)) + be * bu2f(hm.x));
    o.y = f2bs(al * (o1 + bu2f(su.y)) + be * bu2f(hm.y));
    o.z = f2bs(al * (o2 + bu2f(su.z)) + be * bu2f(hm.z));
    o.w = f2bs(al * (o3 + bu2f(su.w)) + be * bu2f(hm.w));
    *(ushort4*)(hf + (size_t)node * 256 + lane * 4) = o;
}

// ---------------------------------------------------------------------------
// Launch
// ---------------------------------------------------------------------------
extern "C" void kernel_launch(void* const* d_in, const int* in_sizes, int n_in,
                              void* d_out, int out_size, void* d_ws, size_t ws_size,
                              hipStream_t stream)
{
    const float* x_g   = (const float*)d_in[0];
    const int*   ei    = (const int*)d_in[1];
    const float* x_m   = (const float*)d_in[2];
    const float* Wq    = (const float*)d_in[3];
    const float* bq    = (const float*)d_in[4];
    const float* Wk    = (const float*)d_in[5];
    const float* bk    = (const float*)d_in[6];
    const float* Wv    = (const float*)d_in[7];
    const float* bv    = (const float*)d_in[8];
    const float* Wskip = (const float*)d_in[9];
    const float* bskip = (const float*)d_in[10];
    const float* W1    = (const float*)d_in[11];
    const float* b1    = (const float*)d_in[12];
    const float* g1    = (const float*)d_in[13];
    const float* be1   = (const float*)d_in[14];
    const float* W2    = (const float*)d_in[15];
    const float* b2    = (const float*)d_in[16];
    const float* g2    = (const float*)d_in[17];
    const float* be2   = (const float*)d_in[18];
    const float* W3    = (const float*)d_in[19];
    const float* b3    = (const float*)d_in[20];
    const float* alpha = (const float*)d_in[21];
    const float* beta  = (const float*)d_in[22];
    const float* Wc1   = (const float*)d_in[23];
    const float* bc1   = (const float*)d_in[24];
    const float* Wc2   = (const float*)d_in[25];
    const float* bc2   = (const float*)d_in[26];
    float* out = (float*)d_out;

    const int N = in_sizes[0] / 256;
    const int E = in_sizes[1] / 2;

    float* ws = (float*)d_ws;
    // bf16 buffers (sizes in float-slots)
    ushort* QKVS = (ushort*)ws;                              // N x 1024 bf16
    ushort* bufA = (ushort*)(ws + (size_t)N * 512);          // N x 512 bf16
    ushort* bufB = (ushort*)(ws + (size_t)N * 512 + (size_t)N * 256); // N x 512
    ushort* hmb  = (ushort*)(ws + (size_t)N * 512 + 2 * (size_t)N * 256); // N x 256
    float* wz = ws + (size_t)N * 512 + 2 * (size_t)N * 256 + (size_t)N * 128;

    float* sum1 = wz, *sq1 = wz + 512, *sum2 = wz + 1024, *sq2 = wz + 1536;
    int* counts = (int*)(wz + 2048);
    float* wz2 = wz + 2048 + N;
    float* scale1 = wz2, *shift1 = wz2 + 512;
    float* scale2 = wz2 + 1024, *shift2 = wz2 + 1536;
    int* bsums = (int*)(wz2 + 2048);
    int* offs = bsums + 256;
    int* cursor = offs + N;
    int* esrc = cursor + N;
    short* Wcat = (short*)(esrc + E);            // 1024 x 256 bf16
    float* bcat = (float*)(Wcat + 1024 * 256);   // 1024 f32
    short* W1b  = (short*)(bcat + 1024);         // 512 x 256
    short* W2b  = W1b + 512 * 256;               // 512 x 512
    short* W3b  = W2b + 512 * 512;               // 256 x 512
    short* Wc1b = W3b + 256 * 512;               // 512 x 256

    dim3 blk(256);
    auto cvt = [&](const float* s, short* d, size_t n) {
        size_t n4 = n / 4;
        int g = (int)((n4 + 255) / 256);
        if (g > 512) g = 512;
        hipLaunchKernelGGL(cvt_f32_bf16, dim3(g), blk, 0, stream, s, (ushort*)d, n4);
    };

    // zero: stats (2048 f32) + counts (N), contiguous
    hipLaunchKernelGGL(zero_words, dim3(128), blk, 0, stream,
                       (unsigned*)wz, (size_t)(2048 + N));

    // weight packing / conversion (all L2-hot afterwards)
    cvt(Wq, Wcat, 256 * 256);
    cvt(Wk, Wcat + 256 * 256, 256 * 256);
    cvt(Wv, Wcat + 512 * 256, 256 * 256);
    cvt(Wskip, Wcat + 768 * 256, 256 * 256);
    cvt(W1, W1b, 512 * 256);
    cvt(W2, W2b, 512 * 512);
    cvt(W3, W3b, 256 * 512);
    cvt(Wc1, Wc1b, 512 * 256);
    hipLaunchKernelGGL(copy_f32, dim3(1), blk, 0, stream, bq, bcat, 256);
    hipLaunchKernelGGL(copy_f32, dim3(1), blk, 0, stream, bk, bcat + 256, 256);
    hipLaunchKernelGGL(copy_f32, dim3(1), blk, 0, stream, bv, bcat + 512, 256);
    hipLaunchKernelGGL(copy_f32, dim3(1), blk, 0, stream, bskip, bcat + 768, 256);

    // CSR build
    const int nb = (N + 255) / 256;
    hipLaunchKernelGGL(count_edges, dim3((E + 255) / 256), blk, 0, stream, ei, counts, E);
    hipLaunchKernelGGL(scan_local, dim3(nb), blk, 0, stream, counts, offs, bsums, N);
    hipLaunchKernelGGL(scan_top, dim3(1), blk, 0, stream, bsums, nb);
    hipLaunchKernelGGL(scan_add, dim3(nb), blk, 0, stream, offs, bsums, cursor, N);
    hipLaunchKernelGGL(fill_edges, dim3((E + 255) / 256), blk, 0, stream, ei, cursor, esrc, E);

    const int g128 = (N + 127) / 128;
    const int g64 = (N + 63) / 64;

    // ---- MLP branch ----
    hipLaunchKernelGGL((gemm_fullk<0, 128, 256>), dim3(g128), blk, 0, stream,
                       x_m, W1b, b1, bufA, N, 4, 0);
    hipLaunchKernelGGL(bn_stats512_b, dim3(512), blk, 0, stream, bufA, sum1, sq1, N);
    hipLaunchKernelGGL(bn_finalize, dim3(2), blk, 0, stream, sum1, sq1, g1, be1, scale1, shift1, N, 512);
    hipLaunchKernelGGL(bn_apply_sig4, dim3(2048), blk, 0, stream, bufA, scale1, shift1, (size_t)N * 128);
    hipLaunchKernelGGL((gemm_fullk<1, 64, 512>), dim3(g64), blk, 0, stream,
                       bufA, W2b, b2, bufB, N, 4, 0);
    hipLaunchKernelGGL(bn_stats512_b, dim3(512), blk, 0, stream, bufB, sum2, sq2, N);
    hipLaunchKernelGGL(bn_finalize, dim3(2), blk, 0, stream, sum2, sq2, g2, be2, scale2, shift2, N, 512);
    hipLaunchKernelGGL(bn_apply_sig4, dim3(2048), blk, 0, stream, bufB, scale2, shift2, (size_t)N * 128);
    hipLaunchKernelGGL((gemm_fullk<1, 64, 512>), dim3(g64), blk, 0, stream,
                       bufB, W3b, b3, hmb, N, 2, 0);

    // ---- GNN branch: fused Q|K|V|S GEMM (A panel read once) ----
    hipLaunchKernelGGL((gemm_fullk<0, 128, 256>), dim3(g128), blk, 0, stream,
                       x_g, Wcat, bcat, QKVS, N, 8, 0);

    // ---- attention + skip + hm fusion -> hf (bufA) ----
    hipLaunchKernelGGL(edge_attn, dim3((N + 3) / 4), blk, 0, stream,
                       esrc, offs, counts, QKVS, hmb, alpha, beta, bufA, N);

    // ---- classifier head ----
    hipLaunchKernelGGL((gemm_fullk<1, 128, 256>), dim3(g128), blk, 0, stream,
                       bufA, Wc1b, bc1, bufB, N, 4, 1);
    hipLaunchKernelGGL(mfma_gemm_small, dim3(1, (N + 127) / 128), blk, 0, stream,
                       (const short*)bufB, Wc2, bc2, out, N, 512, 40);
}